// Round 9
// baseline (1592.986 us; speedup 1.0000x reference)
//
#include <hip/hip_runtime.h>

#define NS 8192
#define TT 128
#define DD 64
#define HH 512
#define BM 16
#define NSTEP (TT - 1)
#define LO_SCALE 2048.0f
#define LO_INV (1.0f / 2048.0f)

typedef _Float16 half8 __attribute__((ext_vector_type(8)));
typedef _Float16 half4 __attribute__((ext_vector_type(4)));
typedef float f32x4 __attribute__((ext_vector_type(4)));

// ws layout (_Float16 elements):
//   W1Th [HH][DD] @ 0        (hi of W1^T)
//   W1Tl [HH][DD] @ 32768    (lo*2048 of W1^T)
//   W2Th [DD][HH] @ 65536    (hi of W2^T)

__global__ __launch_bounds__(256) void prep_weights(
    const float* __restrict__ W1, const float* __restrict__ W2,
    _Float16* __restrict__ wsp) {
  int idx = blockIdx.x * 256 + threadIdx.x;  // 0..65535
  if (idx < HH * DD) {                       // W1[d][j]
    int d = idx / HH, j = idx % HH;
    float w0 = W1[idx];
    _Float16 h = (_Float16)w0;
    float r = (w0 - (float)h) * LO_SCALE;
    wsp[j * DD + d] = h;
    wsp[HH * DD + j * DD + d] = (_Float16)r;
  } else {                                   // W2[j][d] -> hi only
    int k = idx - HH * DD;
    int j = k / DD, d = k % DD;
    wsp[2 * HH * DD + d * HH + j] = (_Float16)W2[k];
  }
}

__device__ __forceinline__ float fast_tanh(float x) {
  float e = __builtin_amdgcn_exp2f(-2.8853900817779268f * fabsf(x));
  float r = (1.0f - e) * __builtin_amdgcn_rcpf(1.0f + e);
  return copysignf(r, x);
}

// BM=16, grid=512, 1024 threads: 2 blocks/CU (2048 thr = HW max) -> 8 waves/EU
// and TWO independent barrier domains per CU. (1024, 8) pins VGPR budget at 64
// (round 8 proved a strictly larger per-wave state fits 64 without spill).
__global__ __launch_bounds__(1024, 8) void ode_mfma_kernel(
    const float* __restrict__ ts, const float* __restrict__ hxs,
    const float* __restrict__ masks, const float* __restrict__ b1,
    const float* __restrict__ b2, const _Float16* __restrict__ wsp,
    float* __restrict__ out) {
  // LDS ~39 KB/block so two blocks co-reside.
  __shared__ __align__(16) _Float16 Zh[BM][520];   // 16.6 KB (520: floor-banked)
  __shared__ __align__(16) _Float16 Yh[BM][72];    //  2.3 KB
  __shared__ __align__(16) float DTs[BM][129];     //  8.3 KB
  __shared__ __align__(16) float Pb[3][4][64][4];  // 12.0 KB 4-way K-split partials

  const int t = threadIdx.x;
  const int w = t >> 6, l = t & 63;   // wave 0..15
  const int c = l & 15, q = l >> 4;
  const int m0 = blockIdx.x * BM;
  // phase-B roles: tile db = w>>2 (0..3), K-quarter ks = w&3
  const int db = w >> 2, ks = w & 3;
  const int m = c;                    // owned sample (phase B / state)
  const int d0 = db * 16 + 4 * q;     // owned dims d0..d0+3

  const _Float16* W1Th = wsp;
  const _Float16* W1Tl = wsp + HH * DD;
  const _Float16* W2Th = wsp + 2 * HH * DD;

  // ---- stationary weight fragments ----
  // phase A: wave w owns col-tiles {2w, 2w+1}
  half8 w1h[2][2], w1l[2][2];
#pragma unroll
  for (int jl = 0; jl < 2; ++jl)
#pragma unroll
    for (int kk = 0; kk < 2; ++kk) {
      int off = ((2 * w + jl) * 16 + c) * DD + kk * 32 + 8 * q;
      w1h[jl][kk] = *(const half8*)&W1Th[off];
      w1l[jl][kk] = *(const half8*)&W1Tl[off];
    }
  // phase B: W2 hi frags for this wave's K-quarter (4 of 16 k-steps)
  half8 w2h[4];
#pragma unroll
  for (int kkl = 0; kkl < 4; ++kkl) {
    int kg = ks * 4 + kkl;
    w2h[kkl] = *(const half8*)&W2Th[(db * 16 + c) * HH + kg * 32 + 8 * q];
  }

  // biases
  f32x4 b1f[2];
#pragma unroll
  for (int jl = 0; jl < 2; ++jl)
    b1f[jl] = *(const f32x4*)&b1[(2 * w + jl) * 16 + 4 * q];
  const f32x4 b2v = *(const f32x4*)&b2[d0];

  // dt table
  for (int idx = t; idx < BM * TT; idx += 1024) {
    int mm = idx >> 7, s = idx & (TT - 1);
    float v = 0.0f;
    if (s < NSTEP) v = ts[(m0 + mm) * TT + s + 1] - ts[(m0 + mm) * TT + s];
    DTs[mm][s] = v;
  }

  // init y-state: ks==0 waves (db 0..3) cover all (m, d0)
  float y[4], f1[4], f2[4], f3[4];
  if (ks == 0) {
    const float mk = masks[m0 + m];
    f32x4 y0 = *(const f32x4*)&hxs[(m0 + m) * DD + d0];
    half4 yh4;
#pragma unroll
    for (int r = 0; r < 4; ++r) {
      y[r] = y0[r] * mk;
      f1[r] = f2[r] = f3[r] = 0.0f;
      yh4[r] = (_Float16)y[r];
    }
    *(half4*)&Yh[m][d0] = yh4;
  }
  __syncthreads();

  for (int s = 0; s < NSTEP; ++s) {
    // ---- phase A (swapped): Z^T tiles = W1^T @ Y^T; 2 col-tiles per wave ----
    {
      half8 yh[2];
#pragma unroll
      for (int kk = 0; kk < 2; ++kk)
        yh[kk] = *(const half8*)&Yh[c][kk * 32 + 8 * q];
#pragma unroll
      for (int jl = 0; jl < 2; ++jl) {
        f32x4 acc1 = b1f[jl];
        f32x4 acc2 = {0.0f, 0.0f, 0.0f, 0.0f};
#pragma unroll
        for (int kk = 0; kk < 2; ++kk) {
          acc1 = __builtin_amdgcn_mfma_f32_16x16x32_f16(w1h[jl][kk], yh[kk], acc1, 0, 0, 0);
          acc2 = __builtin_amdgcn_mfma_f32_16x16x32_f16(w1l[jl][kk], yh[kk], acc2, 0, 0, 0);
        }
        half4 zh4;
#pragma unroll
        for (int r = 0; r < 4; ++r)
          zh4[r] = (_Float16)fast_tanh(acc1[r] + acc2[r] * LO_INV);
        *(half4*)&Zh[c][(2 * w + jl) * 16 + 4 * q] = zh4;
      }
    }
    __syncthreads();

    // ---- phase B (swapped, K-split 4): F^T tile db, K-quarter ks ----
    f32x4 acc = {0.0f, 0.0f, 0.0f, 0.0f};
#pragma unroll
    for (int kkl = 0; kkl < 4; ++kkl) {
      const int kg = ks * 4 + kkl;
      half8 zh = *(const half8*)&Zh[m][kg * 32 + 8 * q];
      acc = __builtin_amdgcn_mfma_f32_16x16x32_f16(w2h[kkl], zh, acc, 0, 0, 0);
    }
    if (ks != 0) {
      *(f32x4*)&Pb[ks - 1][db][l][0] = acc;
    }
    __syncthreads();

    if (ks == 0) {
      const f32x4 p0 = *(const f32x4*)&Pb[0][db][l][0];
      const f32x4 p1 = *(const f32x4*)&Pb[1][db][l][0];
      const f32x4 p2 = *(const f32x4*)&Pb[2][db][l][0];
      const float dtv = DTs[m][s];
      half4 yh4;
#pragma unroll
      for (int r = 0; r < 4; ++r) {
        float fn = acc[r] + p0[r] + p1[r] + p2[r] + b2v[r];
        float inc;
        if (s == 0)      inc = fn;
        else if (s == 1) inc = (3.0f * fn - f1[r]) * 0.5f;
        else if (s == 2) inc = (23.0f * fn - 16.0f * f1[r] + 5.0f * f2[r]) * (1.0f / 12.0f);
        else             inc = (55.0f * fn - 59.0f * f1[r] + 37.0f * f2[r] - 9.0f * f3[r]) * (1.0f / 24.0f);
        y[r] += dtv * inc;
        f3[r] = f2[r]; f2[r] = f1[r]; f1[r] = fn;
        yh4[r] = (_Float16)y[r];
      }
      *(half4*)&Yh[m][d0] = yh4;
    }
    __syncthreads();
  }

  // pred = where(ts[:,0]==0, first_point, y_final); write by ks==0 waves
  if (ks == 0) {
    const float mk = masks[m0 + m];
    float ts0 = ts[(m0 + m) * TT];
    f32x4 o;
    if (ts0 == 0.0f) {
      f32x4 h4 = *(const f32x4*)&hxs[(m0 + m) * DD + d0];
#pragma unroll
      for (int r = 0; r < 4; ++r) o[r] = h4[r] * mk;
    } else {
#pragma unroll
      for (int r = 0; r < 4; ++r) o[r] = y[r];
    }
    *(f32x4*)&out[(m0 + m) * DD + d0] = o;
  }
}

extern "C" void kernel_launch(void* const* d_in, const int* in_sizes, int n_in,
                              void* d_out, int out_size, void* d_ws, size_t ws_size,
                              hipStream_t stream) {
  const float* ts    = (const float*)d_in[0];
  const float* hxs   = (const float*)d_in[1];
  const float* masks = (const float*)d_in[2];
  const float* W1    = (const float*)d_in[3];
  const float* b1    = (const float*)d_in[4];
  const float* W2    = (const float*)d_in[5];
  const float* b2    = (const float*)d_in[6];
  float* out = (float*)d_out;
  _Float16* wsp = (_Float16*)d_ws;
  (void)in_sizes; (void)n_in; (void)out_size; (void)ws_size;

  prep_weights<<<dim3((2 * HH * DD) / 256), dim3(256), 0, stream>>>(W1, W2, wsp);
  ode_mfma_kernel<<<dim3(NS / BM), dim3(1024), 0, stream>>>(ts, hxs, masks, b1, b2, wsp, out);
}

// Round 10
// 293.136 us; speedup vs baseline: 5.4343x; 5.4343x over previous
//
#include <hip/hip_runtime.h>

#define NS 8192
#define TT 128
#define DD 64
#define HH 512
#define BM 16
#define NSTEP (TT - 1)

typedef _Float16 half8 __attribute__((ext_vector_type(8)));
typedef _Float16 half4 __attribute__((ext_vector_type(4)));
typedef float f32x4 __attribute__((ext_vector_type(4)));

// ws layout (_Float16 elements):
//   W1Th [HH][DD] @ 0        (W1^T, fp16)
//   W2Th [DD][HH] @ 32768    (W2^T, fp16)

__global__ __launch_bounds__(256) void prep_weights(
    const float* __restrict__ W1, const float* __restrict__ W2,
    _Float16* __restrict__ wsp) {
  int idx = blockIdx.x * 256 + threadIdx.x;  // 0..65535
  if (idx < HH * DD) {                       // W1[d][j]
    int d = idx / HH, j = idx % HH;
    wsp[j * DD + d] = (_Float16)W1[idx];
  } else {                                   // W2[j][d]
    int k = idx - HH * DD;
    int j = k / DD, d = k % DD;
    wsp[HH * DD + d * HH + j] = (_Float16)W2[k];
  }
}

__device__ __forceinline__ float fast_tanh(float x) {
  float e = __builtin_amdgcn_exp2f(-2.8853900817779268f * fabsf(x));
  float r = (1.0f - e) * __builtin_amdgcn_rcpf(1.0f + e);
  return copysignf(r, x);
}

// BM=16, 512 threads (8 waves), grid=512 -> 2 blocks/CU = 16 waves/CU in TWO
// independent barrier domains. (512,4) -> 128-VGPR budget; long-lived state
// ~84 regs (w1h 32 + w2h 16 + b1f 16 + b2v 4 + y/f1/f2/f3 16) fits without
// the round-9 rematerialization disaster (FETCH tripwire: must be ~4 MB).
__global__ __launch_bounds__(512, 4) void ode_mfma_kernel(
    const float* __restrict__ ts, const float* __restrict__ hxs,
    const float* __restrict__ masks, const float* __restrict__ b1,
    const float* __restrict__ b2, const _Float16* __restrict__ wsp,
    float* __restrict__ out) {
  // LDS ~31.3 KB/block so two blocks co-reside.
  __shared__ __align__(16) _Float16 Zh[BM][520];   // 16.6 KB (520: floor-banked)
  __shared__ __align__(16) _Float16 Yh[BM][72];    //  2.3 KB
  __shared__ __align__(16) float DTs[BM][129];     //  8.3 KB
  __shared__ __align__(16) float Pb[4][64][4];     //  4.0 KB K-split partials

  const int t = threadIdx.x;
  const int w = t >> 6, l = t & 63;   // wave 0..7
  const int c = l & 15, q = l >> 4;
  const int m0 = blockIdx.x * BM;
  // phase-B roles: d-tile db = w>>1 (0..3), K-half ks = w&1
  const int db = w >> 1, ks = w & 1;
  const int m = c;                    // owned sample (phase B / state)
  const int d0 = db * 16 + 4 * q;     // owned dims d0..d0+3

  const _Float16* W1Th = wsp;
  const _Float16* W2Th = wsp + HH * DD;

  // ---- stationary weight fragments ----
  // phase A: wave w owns col-tiles {4w .. 4w+3}
  half8 w1h[4][2];
#pragma unroll
  for (int jl = 0; jl < 4; ++jl)
#pragma unroll
    for (int kk = 0; kk < 2; ++kk) {
      int off = ((4 * w + jl) * 16 + c) * DD + kk * 32 + 8 * q;
      w1h[jl][kk] = *(const half8*)&W1Th[off];
    }
  // phase B: W2 frags for this wave's K-half (8 of 16 k-steps)
  half8 w2h[8];
#pragma unroll
  for (int kkl = 0; kkl < 8; ++kkl) {
    int kg = ks * 8 + kkl;
    w2h[kkl] = *(const half8*)&W2Th[(db * 16 + c) * HH + kg * 32 + 8 * q];
  }

  // biases
  f32x4 b1f[4];
#pragma unroll
  for (int jl = 0; jl < 4; ++jl)
    b1f[jl] = *(const f32x4*)&b1[(4 * w + jl) * 16 + 4 * q];
  const f32x4 b2v = *(const f32x4*)&b2[d0];

  // dt table
  for (int idx = t; idx < BM * TT; idx += 512) {
    int mm = idx >> 7, s = idx & (TT - 1);
    float v = 0.0f;
    if (s < NSTEP) v = ts[(m0 + mm) * TT + s + 1] - ts[(m0 + mm) * TT + s];
    DTs[mm][s] = v;
  }

  // init y-state: ks==0 waves (db 0..3) cover all (m, d0)
  float y[4], f1[4], f2[4], f3[4];
  if (ks == 0) {
    const float mk = masks[m0 + m];
    f32x4 y0 = *(const f32x4*)&hxs[(m0 + m) * DD + d0];
    half4 yh4;
#pragma unroll
    for (int r = 0; r < 4; ++r) {
      y[r] = y0[r] * mk;
      f1[r] = f2[r] = f3[r] = 0.0f;
      yh4[r] = (_Float16)y[r];
    }
    *(half4*)&Yh[m][d0] = yh4;
  }
  __syncthreads();

  for (int s = 0; s < NSTEP; ++s) {
    // ---- phase A (swapped): Z^T tiles = W1^T @ Y^T; 4 col-tiles per wave ----
    {
      half8 yh[2];
#pragma unroll
      for (int kk = 0; kk < 2; ++kk)
        yh[kk] = *(const half8*)&Yh[c][kk * 32 + 8 * q];
#pragma unroll
      for (int jl = 0; jl < 4; ++jl) {
        f32x4 acc = b1f[jl];
#pragma unroll
        for (int kk = 0; kk < 2; ++kk)
          acc = __builtin_amdgcn_mfma_f32_16x16x32_f16(w1h[jl][kk], yh[kk], acc, 0, 0, 0);
        half4 zh4;
#pragma unroll
        for (int r = 0; r < 4; ++r)
          zh4[r] = (_Float16)fast_tanh(acc[r]);
        *(half4*)&Zh[c][(4 * w + jl) * 16 + 4 * q] = zh4;
      }
    }
    __syncthreads();

    // ---- phase B (swapped, K-split 2): F^T tile db, K-half ks ----
    f32x4 acc = {0.0f, 0.0f, 0.0f, 0.0f};
#pragma unroll
    for (int kkl = 0; kkl < 8; ++kkl) {
      const int kg = ks * 8 + kkl;
      half8 zh = *(const half8*)&Zh[m][kg * 32 + 8 * q];
      acc = __builtin_amdgcn_mfma_f32_16x16x32_f16(w2h[kkl], zh, acc, 0, 0, 0);
    }
    if (ks == 1) {
      *(f32x4*)&Pb[db][l][0] = acc;
    }
    __syncthreads();

    if (ks == 0) {
      const f32x4 po = *(const f32x4*)&Pb[db][l][0];
      const float dtv = DTs[m][s];
      half4 yh4;
#pragma unroll
      for (int r = 0; r < 4; ++r) {
        float fn = acc[r] + po[r] + b2v[r];
        float inc;
        if (s == 0)      inc = fn;
        else if (s == 1) inc = (3.0f * fn - f1[r]) * 0.5f;
        else if (s == 2) inc = (23.0f * fn - 16.0f * f1[r] + 5.0f * f2[r]) * (1.0f / 12.0f);
        else             inc = (55.0f * fn - 59.0f * f1[r] + 37.0f * f2[r] - 9.0f * f3[r]) * (1.0f / 24.0f);
        y[r] += dtv * inc;
        f3[r] = f2[r]; f2[r] = f1[r]; f1[r] = fn;
        yh4[r] = (_Float16)y[r];
      }
      *(half4*)&Yh[m][d0] = yh4;
    }
    __syncthreads();
  }

  // pred = where(ts[:,0]==0, first_point, y_final); write by ks==0 waves
  if (ks == 0) {
    const float mk = masks[m0 + m];
    float ts0 = ts[(m0 + m) * TT];
    f32x4 o;
    if (ts0 == 0.0f) {
      f32x4 h4 = *(const f32x4*)&hxs[(m0 + m) * DD + d0];
#pragma unroll
      for (int r = 0; r < 4; ++r) o[r] = h4[r] * mk;
    } else {
#pragma unroll
      for (int r = 0; r < 4; ++r) o[r] = y[r];
    }
    *(f32x4*)&out[(m0 + m) * DD + d0] = o;
  }
}

extern "C" void kernel_launch(void* const* d_in, const int* in_sizes, int n_in,
                              void* d_out, int out_size, void* d_ws, size_t ws_size,
                              hipStream_t stream) {
  const float* ts    = (const float*)d_in[0];
  const float* hxs   = (const float*)d_in[1];
  const float* masks = (const float*)d_in[2];
  const float* W1    = (const float*)d_in[3];
  const float* b1    = (const float*)d_in[4];
  const float* W2    = (const float*)d_in[5];
  const float* b2    = (const float*)d_in[6];
  float* out = (float*)d_out;
  _Float16* wsp = (_Float16*)d_ws;
  (void)in_sizes; (void)n_in; (void)out_size; (void)ws_size;

  prep_weights<<<dim3((2 * HH * DD) / 256), dim3(256), 0, stream>>>(W1, W2, wsp);
  ode_mfma_kernel<<<dim3(NS / BM), dim3(512), 0, stream>>>(ts, hxs, masks, b1, b2, wsp, out);
}